// Round 1
// baseline (240.677 us; speedup 1.0000x reference)
//
#include <hip/hip_runtime.h>
#include <cstddef>

#define BH 4
#define CH 64
#define OH 64
#define HH 128
#define WW 128
#define KK 9
#define KDIM (CH * KK)   // 576
#define HW (HH * WW)     // 16384

// ---------------------------------------------------------------------------
// Transpose x[b][c][h][w] -> xt[b][h][w][c]  (NCHW -> NHWC)
// One block per (b, 64-pixel chunk): 64x64 tile through LDS.
// ---------------------------------------------------------------------------
__global__ __launch_bounds__(256) void dcl_transpose(const float* __restrict__ x,
                                                     float* __restrict__ xt) {
    __shared__ float tile[64][65];
    int chunk = blockIdx.x;              // 0 .. B*HW/64-1 = 1023
    int b = chunk >> 8;                  // 256 chunks per batch
    int hw0 = (chunk & 255) * 64;
    int tx = threadIdx.x;                // 0..63
    int ty = threadIdx.y;                // 0..3
    const float* xb = x + (size_t)b * CH * HW;
    for (int c = ty; c < 64; c += 4)
        tile[c][tx] = xb[(size_t)c * HW + hw0 + tx];
    __syncthreads();
    float* xtb = xt + (size_t)b * HW * CH;
    for (int i = ty; i < 64; i += 4)
        xtb[(size_t)(hw0 + i) * CH + tx] = tile[tx][i];
}

// ---------------------------------------------------------------------------
// Reorganize weight[o][c][kt] (o*64*9) -> wt[k][o] with k = kt*64 + c
// ---------------------------------------------------------------------------
__global__ __launch_bounds__(256) void dcl_wreorg(const float* __restrict__ wgt,
                                                  float* __restrict__ wt) {
    int idx = blockIdx.x * 256 + threadIdx.x;   // 0 .. 64*576-1
    if (idx >= OH * KDIM) return;
    int o = idx & 63;
    int k = idx >> 6;
    int c = k & 63;
    int t = k >> 6;
    wt[idx] = wgt[(o * CH + c) * KK + t];
}

// ---------------------------------------------------------------------------
// Main kernel. Block = 256 threads = 4 waves, 16 pixels per block.
// Stage 1: wave w samples pixels 4w..4w+3 (lane = channel) -> s_lds[p][k]
// Stage 2: thread (o = lane) accumulates 4 pixels over K=576.
// USE_XT: sample from NHWC copy (fast) or raw NCHW x (fallback).
// ---------------------------------------------------------------------------
template <bool USE_XT>
__global__ __launch_bounds__(256) void dcl_main(const float* __restrict__ xsrc,
                                                const float* __restrict__ offset,
                                                const float* __restrict__ wt,     // may be null
                                                const float* __restrict__ wraw,
                                                const float* __restrict__ bias,
                                                float* __restrict__ out) {
    __shared__ float s_lds[16][KDIM];     // 36 KiB, rows are wave-private
    __shared__ float o_lds[16][OH + 1];   // padded: epilogue reads stride-65

    int tid = threadIdx.x;
    int lane = tid & 63;
    int wave = tid >> 6;
    int P0 = blockIdx.x * 16;

    // ---- Stage 1: bilinear gather ----
    for (int pp = 0; pp < 4; ++pp) {
        int p = wave * 4 + pp;
        int P = P0 + p;
        int b = P >> 14;
        int rem = P & (HW - 1);
        int y = rem >> 7;
        int x = rem & 127;
        const float* offb = offset + (size_t)b * 18 * HW + rem;
        const float* xb = USE_XT ? (xsrc + (size_t)b * HW * CH)
                                 : (xsrc + (size_t)b * CH * HW);
#pragma unroll
        for (int t = 0; t < 9; ++t) {
            float ox = offb[(size_t)(2 * t) * HW];
            float oy = offb[(size_t)(2 * t + 1) * HW];
            float px = (float)x + ox;
            float py = (float)y + oy;
            float x0f = floorf(px), y0f = floorf(py);
            float wx1 = px - x0f, wy1 = py - y0f;
            float wx0 = 1.0f - wx1, wy0 = 1.0f - wy1;
            int ix0 = (int)x0f, iy0 = (int)y0f;
            int ix1 = ix0 + 1, iy1 = iy0 + 1;
            bool vx0 = (unsigned)ix0 < (unsigned)WW;
            bool vx1 = (unsigned)ix1 < (unsigned)WW;
            bool vy0 = (unsigned)iy0 < (unsigned)HH;
            bool vy1 = (unsigned)iy1 < (unsigned)HH;
            float v00, v10, v01, v11;
            if (USE_XT) {
                v00 = (vx0 && vy0) ? xb[(size_t)(iy0 * WW + ix0) * CH + lane] : 0.0f;
                v10 = (vx1 && vy0) ? xb[(size_t)(iy0 * WW + ix1) * CH + lane] : 0.0f;
                v01 = (vx0 && vy1) ? xb[(size_t)(iy1 * WW + ix0) * CH + lane] : 0.0f;
                v11 = (vx1 && vy1) ? xb[(size_t)(iy1 * WW + ix1) * CH + lane] : 0.0f;
            } else {
                const float* xc = xb + (size_t)lane * HW;
                v00 = (vx0 && vy0) ? xc[iy0 * WW + ix0] : 0.0f;
                v10 = (vx1 && vy0) ? xc[iy0 * WW + ix1] : 0.0f;
                v01 = (vx0 && vy1) ? xc[iy1 * WW + ix0] : 0.0f;
                v11 = (vx1 && vy1) ? xc[iy1 * WW + ix1] : 0.0f;
            }
            float s = (v00 * wx0 + v10 * wx1) * wy0 + (v01 * wx0 + v11 * wx1) * wy1;
            s_lds[p][t * 64 + lane] = s;
        }
    }
    // No barrier needed: stage 2 reads only this wave's own rows of s_lds.

    // ---- Stage 2: contraction (o = lane, 4 pixels) ----
    float acc0 = 0.f, acc1 = 0.f, acc2 = 0.f, acc3 = 0.f;
    int pbase = wave * 4;
    if (wt != nullptr) {
        const float* wcol = wt + lane;
#pragma unroll 4
        for (int k = 0; k < KDIM; k += 4) {
            float w0 = wcol[(size_t)(k + 0) * 64];
            float w1 = wcol[(size_t)(k + 1) * 64];
            float w2 = wcol[(size_t)(k + 2) * 64];
            float w3 = wcol[(size_t)(k + 3) * 64];
            float4 s0 = *(const float4*)&s_lds[pbase + 0][k];
            float4 s1 = *(const float4*)&s_lds[pbase + 1][k];
            float4 s2 = *(const float4*)&s_lds[pbase + 2][k];
            float4 s3 = *(const float4*)&s_lds[pbase + 3][k];
            acc0 += w0 * s0.x + w1 * s0.y + w2 * s0.z + w3 * s0.w;
            acc1 += w0 * s1.x + w1 * s1.y + w2 * s1.z + w3 * s1.w;
            acc2 += w0 * s2.x + w1 * s2.y + w2 * s2.z + w3 * s2.w;
            acc3 += w0 * s3.x + w1 * s3.y + w2 * s3.z + w3 * s3.w;
        }
    } else {
        // Fallback: read raw weight[o][c][t]
        for (int k = 0; k < KDIM; ++k) {
            int c = k & 63, t = k >> 6;
            float wv = wraw[(lane * CH + c) * KK + t];
            acc0 += wv * s_lds[pbase + 0][k];
            acc1 += wv * s_lds[pbase + 1][k];
            acc2 += wv * s_lds[pbase + 2][k];
            acc3 += wv * s_lds[pbase + 3][k];
        }
    }
    float bv = bias[lane];
    o_lds[pbase + 0][lane] = acc0 + bv;
    o_lds[pbase + 1][lane] = acc1 + bv;
    o_lds[pbase + 2][lane] = acc2 + bv;
    o_lds[pbase + 3][lane] = acc3 + bv;
    __syncthreads();

    // ---- Epilogue: coalesced NCHW write (16 consecutive x per 16 lanes) ----
    int Pb = P0;
    int b = Pb >> 14;
    int rem0 = Pb & (HW - 1);
#pragma unroll
    for (int j = tid; j < 16 * 64; j += 256) {
        int o = j >> 4;
        int p = j & 15;
        out[((size_t)(b * OH + o) << 14) + rem0 + p] = o_lds[p][o];
    }
}

extern "C" void kernel_launch(void* const* d_in, const int* in_sizes, int n_in,
                              void* d_out, int out_size, void* d_ws, size_t ws_size,
                              hipStream_t stream) {
    const float* x      = (const float*)d_in[0];
    const float* offset = (const float*)d_in[1];
    const float* weight = (const float*)d_in[2];
    const float* bias   = (const float*)d_in[3];
    float* out = (float*)d_out;

    const size_t need_xt = (size_t)BH * HW * CH * sizeof(float);   // 16.8 MB
    const size_t need_wt = (size_t)OH * KDIM * sizeof(float);      // 144 KiB

    int nblocks = (BH * HW) / 16;   // 4096

    if (ws_size >= need_xt + need_wt) {
        float* xt = (float*)d_ws;
        float* wt = (float*)((char*)d_ws + need_xt);
        dcl_transpose<<<(BH * HW) / 64, dim3(64, 4), 0, stream>>>(x, xt);
        dcl_wreorg<<<(OH * KDIM + 255) / 256, 256, 0, stream>>>(weight, wt);
        dcl_main<true><<<nblocks, 256, 0, stream>>>(xt, offset, wt, weight, bias, out);
    } else if (ws_size >= need_wt) {
        float* wt = (float*)d_ws;
        dcl_wreorg<<<(OH * KDIM + 255) / 256, 256, 0, stream>>>(weight, wt);
        dcl_main<false><<<nblocks, 256, 0, stream>>>(x, offset, wt, weight, bias, out);
    } else {
        dcl_main<false><<<nblocks, 256, 0, stream>>>(x, offset, nullptr, weight, bias, out);
    }
}